// Round 5
// baseline (203.076 us; speedup 1.0000x reference)
//
#include <hip/hip_runtime.h>

// BatchDelayProcessor: out[b,t] = x[b,t]*(1-MIX) + delayed[b,t]*MIX
//   delayed[t<D] = 0 ; delayed[t] = x[t-D] + FB*delayed[t-D]
// => per (b, i) column, a 20-step serial scan over blocks of D samples.
//
// R1: 1-deep prefetch -> 20 serial HBM latencies, 2.44 TB/s (31% peak).
// R2: load-all-then-compute in source; scheduler sank loads to uses
//     (VGPR stayed 20) -> unchanged. All 20 addresses are independent;
//     only the (trivial) FMA carry chain is serial -> pure MLP problem.
// R3/R4: sched_barrier(0) fence -> kernel still ~70us (inferred; fell out
//     of top-5 but harness total unchanged). Fence didn't bind.
// R5: scheduler-proof fence: ONE asm volatile reading all 40 scalar
//     components of the 20 loaded float2s. Loads cannot sink past their
//     use -> all 20 global_load_dwordx2 issue back-to-back, one
//     s_waitcnt vmcnt(0), then the register-only scan. ~56 VGPR (<=64
//     keeps 8 waves/SIMD).

constexpr int   kB    = 64;
constexpr int   kT    = 441000;
constexpr int   kD    = 22050;          // delay in samples
constexpr int   kNBLK = kT / kD;        // 20 blocks
constexpr float kFB   = 0.3f;
constexpr float kMIX  = 0.5f;

// float2 granularity: D = 22050 is even and every block offset k*D is even
// -> 8B-aligned float2 everywhere. (float4 impossible: D % 4 == 2.)
constexpr int kHALF  = kD / 2;          // 11025 float2 columns per block
constexpr int kTOTAL = kB * kHALF;      // 705600 threads

__global__ __launch_bounds__(256)
void delay_scan_kernel(const float* __restrict__ x, float* __restrict__ out) {
    int tid = blockIdx.x * blockDim.x + threadIdx.x;
    if (tid >= kTOTAL) return;
    int b = tid / kHALF;                // magic-mul div, once per thread
    int i = tid - b * kHALF;

    const float2* __restrict__ xp =
        reinterpret_cast<const float2*>(x + (size_t)b * kT) + i;
    float2* __restrict__ op =
        reinterpret_cast<float2*>(out + (size_t)b * kT) + i;

    constexpr int kSTRIDE2 = kD / 2;    // float2 stride between blocks

    // Phase 1: issue all 20 independent loads back-to-back (20-deep MLP).
    float2 xv[kNBLK];
    #pragma unroll
    for (int k = 0; k < kNBLK; ++k)
        xv[k] = xp[(size_t)k * kSTRIDE2];

    // Liveness fence: this single asm READS every loaded component, so all
    // 20 loads must be issued and completed before this point. The
    // scheduler cannot sink any load past its use. One statement only --
    // per-load asms would re-serialize (each forces its own waitcnt).
    asm volatile(""
        :: "v"(xv[0].x),  "v"(xv[0].y),  "v"(xv[1].x),  "v"(xv[1].y),
           "v"(xv[2].x),  "v"(xv[2].y),  "v"(xv[3].x),  "v"(xv[3].y),
           "v"(xv[4].x),  "v"(xv[4].y),  "v"(xv[5].x),  "v"(xv[5].y),
           "v"(xv[6].x),  "v"(xv[6].y),  "v"(xv[7].x),  "v"(xv[7].y),
           "v"(xv[8].x),  "v"(xv[8].y),  "v"(xv[9].x),  "v"(xv[9].y),
           "v"(xv[10].x), "v"(xv[10].y), "v"(xv[11].x), "v"(xv[11].y),
           "v"(xv[12].x), "v"(xv[12].y), "v"(xv[13].x), "v"(xv[13].y),
           "v"(xv[14].x), "v"(xv[14].y), "v"(xv[15].x), "v"(xv[15].y),
           "v"(xv[16].x), "v"(xv[16].y), "v"(xv[17].x), "v"(xv[17].y),
           "v"(xv[18].x), "v"(xv[18].y), "v"(xv[19].x), "v"(xv[19].y));

    // Phase 2: serial lag-D recurrence entirely in registers + stores.
    float2 carry; carry.x = 0.0f; carry.y = 0.0f;
    #pragma unroll
    for (int k = 0; k < kNBLK; ++k) {
        float2 o;
        o.x = xv[k].x * (1.0f - kMIX) + carry.x * kMIX;
        o.y = xv[k].y * (1.0f - kMIX) + carry.y * kMIX;
        op[(size_t)k * kSTRIDE2] = o;

        carry.x = xv[k].x + kFB * carry.x;
        carry.y = xv[k].y + kFB * carry.y;
    }
}

extern "C" void kernel_launch(void* const* d_in, const int* in_sizes, int n_in,
                              void* d_out, int out_size, void* d_ws, size_t ws_size,
                              hipStream_t stream) {
    const float* x = (const float*)d_in[0];
    float* out = (float*)d_out;

    constexpr int kBlock = 256;
    constexpr int kGrid  = (kTOTAL + kBlock - 1) / kBlock;  // 2757 blocks
    delay_scan_kernel<<<kGrid, kBlock, 0, stream>>>(x, out);
}